// Round 4
// baseline (30.858 us; speedup 1.0000x reference)
//
#include <hip/hip_runtime.h>
#include <hip/hip_bf16.h>
#include <float.h>

// YOLO-style detector decode, 3 scales.
// Scale s: input [B=32, C=255=3*85, H, W], H=W in {13,26,52}
// Output row r (concatenated over scales) = [conf, x1, y1, x2, y2, cls]
// or all-zero if conf <= thresh. Row order: ((b*H+h)*W+w)*3 + a.
//
// Round 3: wave = contiguous hw for one (b,anchor) -> 29us.
// Round 4: float4 over hw for the 26/52 scales (channel stride 16B-aligned):
// 1KB per wave vmem instr, 4x fewer loads, 4x bytes-in-flight per wave.
// 13-scale (HW=169, 5% of work) stays scalar.

#define NUM_B 32
#define NUM_CLS 80
#define CH 255

#define R13 (NUM_B * 13 * 13 * 3)             // 16224
#define R26 (NUM_B * 26 * 26 * 3)             // 64896
#define CUM13 R13                              // 16224
#define CUM26 (R13 + R26)                      // 81120

// blocks: scalar 13-scale: 96; vec4 26-scale: 96; vec4 52-scale: 288
#define NBLK13 (NUM_B * 3)                     // 96   (169 lanes)
#define NBLK26 (NUM_B * 3)                     // 96   (676/4=169 quads)
#define NBLK52 (NUM_B * 3 * 3)                 // 288  (2704/4=676 quads, 3 tiles)

// ---------------- scalar path (13x13) ----------------
template <int H, int AOFF>
__device__ __forceinline__ void decode_tile_s(
    const float* __restrict__ in,
    const float* __restrict__ anchors,
    float thresh, float step,
    int idx,                    // (b*3+a)
    float* __restrict__ outs)   // scale-local output base
{
    constexpr int W  = H;
    constexpr int HW = H * W;

    const int a = idx % 3;
    const int b = idx / 3;

    const int hw = threadIdx.x;
    if (hw >= HW) return;

    const float* p = in + ((size_t)(b * CH + a * 85)) * HW + hw;

    const float conf = p[0];
    const float tx   = p[1 * HW];
    const float ty   = p[2 * HW];
    const float tw   = p[3 * HW];
    const float th   = p[4 * HW];

    const float* pc = p + 5 * HW;
    float best = -FLT_MAX;
    int   bi   = 0;
    #pragma unroll
    for (int c0 = 0; c0 < NUM_CLS; c0 += 16) {
        float v[16];
        #pragma unroll
        for (int k = 0; k < 16; ++k)
            v[k] = pc[(size_t)(c0 + k) * HW];
        #pragma unroll
        for (int k = 0; k < 16; ++k)
            if (v[k] > best) { best = v[k]; bi = c0 + k; }
    }

    const int wi = hw % W;
    const int hi = hw / W;

    const float cx = ((float)wi + tx) * step;
    const float cy = ((float)hi + ty) * step;
    const float aw = anchors[AOFF + a * 2 + 0] * __expf(tw);
    const float ah = anchors[AOFF + a * 2 + 1] * __expf(th);

    const float x1 = cx - aw * 0.5f;
    const float y1 = cy - ah * 0.5f;
    const float x2 = x1 + aw;
    const float y2 = y1 + ah;

    const bool m = conf > thresh;
    float2* o2 = (float2*)(outs + ((size_t)(b * HW + hw) * 3 + a) * 6);
    o2[0] = m ? make_float2(conf, x1)      : make_float2(0.f, 0.f);
    o2[1] = m ? make_float2(y1, x2)        : make_float2(0.f, 0.f);
    o2[2] = m ? make_float2(y2, (float)bi) : make_float2(0.f, 0.f);
}

// ---------------- float4 path (26x26, 52x52) ----------------
template <int H, int AOFF, int NTILE>
__device__ __forceinline__ void decode_tile_v4(
    const float* __restrict__ in,
    const float* __restrict__ anchors,
    float thresh, float step,
    int idx,                    // (b*3+a)*NTILE + tile
    float* __restrict__ outs)   // scale-local output base
{
    constexpr int W   = H;
    constexpr int HW  = H * W;
    constexpr int HW4 = HW / 4;   // HW divisible by 4 for H=26,52

    const int tile = idx % NTILE;
    const int ba   = idx / NTILE;
    const int a    = ba % 3;      // wave-uniform
    const int b    = ba / 3;      // wave-uniform

    const int q = tile * 256 + threadIdx.x;   // quad index within (b,a)
    if (q >= HW4) return;

    // slab base is 16B aligned: HW*4B is a multiple of 16 for H=26,52
    const float4* p = (const float4*)(in + ((size_t)(b * CH + a * 85)) * HW) + q;

    const float4 conf4 = p[0];
    const float4 tx4   = p[1 * HW4];
    const float4 ty4   = p[2 * HW4];
    const float4 tw4   = p[3 * HW4];
    const float4 th4   = p[4 * HW4];

    // per-lane argmax over 80 classes, 20-class register batches
    const float4* pc = p + 5 * HW4;
    float best[4] = {-FLT_MAX, -FLT_MAX, -FLT_MAX, -FLT_MAX};
    int   bi[4]   = {0, 0, 0, 0};
    #pragma unroll
    for (int c0 = 0; c0 < NUM_CLS; c0 += 20) {
        float4 v[20];
        #pragma unroll
        for (int k = 0; k < 20; ++k)
            v[k] = pc[(size_t)(c0 + k) * HW4];
        #pragma unroll
        for (int k = 0; k < 20; ++k) {
            const float vv[4] = {v[k].x, v[k].y, v[k].z, v[k].w};
            #pragma unroll
            for (int i = 0; i < 4; ++i)
                if (vv[i] > best[i]) { best[i] = vv[i]; bi[i] = c0 + k; }
        }
    }

    const float aw_a = anchors[AOFF + a * 2 + 0];
    const float ah_a = anchors[AOFF + a * 2 + 1];

    const float cf[4] = {conf4.x, conf4.y, conf4.z, conf4.w};
    const float tx[4] = {tx4.x, tx4.y, tx4.z, tx4.w};
    const float ty[4] = {ty4.x, ty4.y, ty4.z, ty4.w};
    const float tw[4] = {tw4.x, tw4.y, tw4.z, tw4.w};
    const float th[4] = {th4.x, th4.y, th4.z, th4.w};

    #pragma unroll
    for (int i = 0; i < 4; ++i) {
        const int hw = 4 * q + i;
        const int wi = hw % W;
        const int hi = hw / W;

        const float cx = ((float)wi + tx[i]) * step;
        const float cy = ((float)hi + ty[i]) * step;
        const float aw = aw_a * __expf(tw[i]);
        const float ah = ah_a * __expf(th[i]);

        const float x1 = cx - aw * 0.5f;
        const float y1 = cy - ah * 0.5f;
        const float x2 = x1 + aw;
        const float y2 = y1 + ah;

        const bool m = cf[i] > thresh;
        float2* o2 = (float2*)(outs + ((size_t)(b * HW + hw) * 3 + a) * 6);
        o2[0] = m ? make_float2(cf[i], x1)        : make_float2(0.f, 0.f);
        o2[1] = m ? make_float2(y1, x2)           : make_float2(0.f, 0.f);
        o2[2] = m ? make_float2(y2, (float)bi[i]) : make_float2(0.f, 0.f);
    }
}

__global__ __launch_bounds__(256) void detector_decode(
    const float* __restrict__ in13,
    const float* __restrict__ in26,
    const float* __restrict__ in52,
    const float* __restrict__ anchors,   // [3,3,2] flat
    float* __restrict__ out)             // [TOTAL, 6] flat
{
    const int bid = blockIdx.x;
    if (bid < NBLK13) {
        decode_tile_s<13, 0>(in13, anchors, 0.5f, 32.0f, bid, out);
    } else if (bid < NBLK13 + NBLK26) {
        decode_tile_v4<26, 6, 1>(in26, anchors, 0.5f, 16.0f, bid - NBLK13,
                                 out + (size_t)CUM13 * 6);
    } else {
        decode_tile_v4<52, 12, 3>(in52, anchors, 0.9f, 8.0f,
                                  bid - (NBLK13 + NBLK26),
                                  out + (size_t)CUM26 * 6);
    }
}

extern "C" void kernel_launch(void* const* d_in, const int* in_sizes, int n_in,
                              void* d_out, int out_size, void* d_ws, size_t ws_size,
                              hipStream_t stream) {
    const float* in13    = (const float*)d_in[0];
    const float* in26    = (const float*)d_in[1];
    const float* in52    = (const float*)d_in[2];
    const float* anchors = (const float*)d_in[3];
    float* out = (float*)d_out;

    const int blocks = NBLK13 + NBLK26 + NBLK52;   // 480
    detector_decode<<<blocks, 256, 0, stream>>>(in13, in26, in52, anchors, out);
}

// Round 5
// 28.762 us; speedup vs baseline: 1.0729x; 1.0729x over previous
//
#include <hip/hip_runtime.h>
#include <hip/hip_bf16.h>
#include <float.h>

// YOLO-style detector decode, 3 scales.
// Scale s: input [B=32, C=255=3*85, H, W], H=W in {13,26,52}
// Output row r (concatenated over scales) = [conf, x1, y1, x2, y2, cls]
// or all-zero if conf <= thresh. Row order: ((b*H+h)*W+w)*3 + a.
//
// Round 3 (scalar, 5324 waves): 29us.  Round 4 (float4, 1331 waves): 31us,
// occupancy 6.8% -> latency-bound, nothing to hide latency with.
// Round 5: float4 AND high wave count: the 80-class argmax is split 4-ways
// across lane groups (lane = cc*16 + qlow, cc handles classes [20cc,20cc+20)),
// combined with 2 shfl_xor rounds. Grid back to 1440 blocks / 5760 waves.

#define NUM_B 32
#define NUM_CLS 80
#define CH 255

#define R13 (NUM_B * 13 * 13 * 3)             // 16224
#define R26 (NUM_B * 26 * 26 * 3)             // 64896
#define CUM13 R13                              // 16224
#define CUM26 (R13 + R26)                      // 81120

// blocks: 13-scale scalar: 96; class-split v4: 26-scale 3 tiles, 52-scale 11
// tiles of 64 quads per block.
#define NBLK13 (NUM_B * 3)                     // 96
#define NBLK26 (NUM_B * 3 * 3)                 // 288  (169 quads -> 3 tiles)
#define NBLK52 (NUM_B * 3 * 11)                // 1056 (676 quads -> 11 tiles)

// ---------------- scalar path (13x13, 5% of work) ----------------
template <int H, int AOFF>
__device__ __forceinline__ void decode_tile_s(
    const float* __restrict__ in,
    const float* __restrict__ anchors,
    float thresh, float step,
    int idx,                    // (b*3+a)
    float* __restrict__ outs)   // scale-local output base
{
    constexpr int W  = H;
    constexpr int HW = H * W;

    const int a = idx % 3;
    const int b = idx / 3;

    const int hw = threadIdx.x;
    if (hw >= HW) return;

    const float* p = in + ((size_t)(b * CH + a * 85)) * HW + hw;

    const float conf = p[0];
    const float tx   = p[1 * HW];
    const float ty   = p[2 * HW];
    const float tw   = p[3 * HW];
    const float th   = p[4 * HW];

    const float* pc = p + 5 * HW;
    float best = -FLT_MAX;
    int   bi   = 0;
    #pragma unroll
    for (int c0 = 0; c0 < NUM_CLS; c0 += 16) {
        float v[16];
        #pragma unroll
        for (int k = 0; k < 16; ++k)
            v[k] = pc[(size_t)(c0 + k) * HW];
        #pragma unroll
        for (int k = 0; k < 16; ++k)
            if (v[k] > best) { best = v[k]; bi = c0 + k; }
    }

    const int wi = hw % W;
    const int hi = hw / W;

    const float cx = ((float)wi + tx) * step;
    const float cy = ((float)hi + ty) * step;
    const float aw = anchors[AOFF + a * 2 + 0] * __expf(tw);
    const float ah = anchors[AOFF + a * 2 + 1] * __expf(th);

    const float x1 = cx - aw * 0.5f;
    const float y1 = cy - ah * 0.5f;
    const float x2 = x1 + aw;
    const float y2 = y1 + ah;

    const bool m = conf > thresh;
    float2* o2 = (float2*)(outs + ((size_t)(b * HW + hw) * 3 + a) * 6);
    o2[0] = m ? make_float2(conf, x1)      : make_float2(0.f, 0.f);
    o2[1] = m ? make_float2(y1, x2)        : make_float2(0.f, 0.f);
    o2[2] = m ? make_float2(y2, (float)bi) : make_float2(0.f, 0.f);
}

// ------- float4 + 4-way class-split path (26x26, 52x52) -------
// Wave layout: lane = cc*16 + qlow. Each wave covers 16 quads (64 elements);
// lane group cc does the argmax over classes [20cc, 20cc+20) for its quad.
// Block (256 thr, 4 waves) covers 64 quads.
template <int H, int AOFF, int NTILE>
__device__ __forceinline__ void decode_tile_v4cs(
    const float* __restrict__ in,
    const float* __restrict__ anchors,
    float thresh, float step,
    int idx,                    // (b*3+a)*NTILE + tile
    float* __restrict__ outs)   // scale-local output base
{
    constexpr int W   = H;
    constexpr int HW  = H * W;
    constexpr int HW4 = HW / 4;   // divisible by 4 for H=26,52

    const int tile = idx % NTILE;
    const int ba   = idx / NTILE;
    const int a    = ba % 3;      // wave-uniform
    const int b    = ba / 3;      // wave-uniform

    const int lane = threadIdx.x & 63;
    const int wv   = threadIdx.x >> 6;
    const int cc   = lane >> 4;   // class chunk 0..3
    const int ql   = lane & 15;

    const int qbase = tile * 64 + wv * 16;
    if (qbase >= HW4) return;     // wave-uniform early out (tail tiles)

    const int  q   = qbase + ql;
    const bool act = (q < HW4);
    const int  qc  = act ? q : (HW4 - 1);   // clamp: keep loads in-bounds

    const float4* slab =
        (const float4*)(in + ((size_t)(b * CH + a * 85)) * HW);

    // conf + box: same address across the 4 cc groups -> coalesces to one
    // 256B segment per instr; issued up front so latency overlaps argmax.
    const float4* p = slab + qc;
    const float4 conf4 = p[0];
    const float4 tx4   = p[1 * HW4];
    const float4 ty4   = p[2 * HW4];
    const float4 tw4   = p[3 * HW4];
    const float4 th4   = p[4 * HW4];

    // own 20 classes, 2 batches of 10 float4 (keeps VGPR ~<128)
    const float4* pc = slab + (size_t)(5 + cc * 20) * HW4 + qc;
    float best[4] = {-FLT_MAX, -FLT_MAX, -FLT_MAX, -FLT_MAX};
    int   bi[4]   = {0, 0, 0, 0};
    #pragma unroll
    for (int c0 = 0; c0 < 20; c0 += 10) {
        float4 v[10];
        #pragma unroll
        for (int k = 0; k < 10; ++k)
            v[k] = pc[(size_t)(c0 + k) * HW4];
        #pragma unroll
        for (int k = 0; k < 10; ++k) {
            const float vv[4] = {v[k].x, v[k].y, v[k].z, v[k].w};
            #pragma unroll
            for (int i = 0; i < 4; ++i)
                if (vv[i] > best[i]) { best[i] = vv[i]; bi[i] = cc * 20 + c0 + k; }
        }
    }

    // combine the 4 chunk results: lanes {l, l^16, l^32, l^48} hold the same
    // quad. Tie-break on lower class index = first-max-wins (jnp.argmax).
    #pragma unroll
    for (int off = 16; off <= 32; off <<= 1) {
        #pragma unroll
        for (int i = 0; i < 4; ++i) {
            const float ob  = __shfl_xor(best[i], off, 64);
            const int   obi = __shfl_xor(bi[i],   off, 64);
            if (ob > best[i] || (ob == best[i] && obi < bi[i])) {
                best[i] = ob; bi[i] = obi;
            }
        }
    }

    if (cc != 0 || !act) return;

    const float aw_a = anchors[AOFF + a * 2 + 0];
    const float ah_a = anchors[AOFF + a * 2 + 1];

    const float cf[4] = {conf4.x, conf4.y, conf4.z, conf4.w};
    const float tx[4] = {tx4.x, tx4.y, tx4.z, tx4.w};
    const float ty[4] = {ty4.x, ty4.y, ty4.z, ty4.w};
    const float tw[4] = {tw4.x, tw4.y, tw4.z, tw4.w};
    const float th[4] = {th4.x, th4.y, th4.z, th4.w};

    #pragma unroll
    for (int i = 0; i < 4; ++i) {
        const int hw = 4 * qc + i;
        const int wi = hw % W;
        const int hi = hw / W;

        const float cx = ((float)wi + tx[i]) * step;
        const float cy = ((float)hi + ty[i]) * step;
        const float aw = aw_a * __expf(tw[i]);
        const float ah = ah_a * __expf(th[i]);

        const float x1 = cx - aw * 0.5f;
        const float y1 = cy - ah * 0.5f;
        const float x2 = x1 + aw;
        const float y2 = y1 + ah;

        const bool m = cf[i] > thresh;
        float2* o2 = (float2*)(outs + ((size_t)(b * HW + hw) * 3 + a) * 6);
        o2[0] = m ? make_float2(cf[i], x1)         : make_float2(0.f, 0.f);
        o2[1] = m ? make_float2(y1, x2)            : make_float2(0.f, 0.f);
        o2[2] = m ? make_float2(y2, (float)bi[i])  : make_float2(0.f, 0.f);
    }
}

__global__ __launch_bounds__(256) void detector_decode(
    const float* __restrict__ in13,
    const float* __restrict__ in26,
    const float* __restrict__ in52,
    const float* __restrict__ anchors,   // [3,3,2] flat
    float* __restrict__ out)             // [TOTAL, 6] flat
{
    const int bid = blockIdx.x;
    if (bid < NBLK13) {
        decode_tile_s<13, 0>(in13, anchors, 0.5f, 32.0f, bid, out);
    } else if (bid < NBLK13 + NBLK26) {
        decode_tile_v4cs<26, 6, 3>(in26, anchors, 0.5f, 16.0f, bid - NBLK13,
                                   out + (size_t)CUM13 * 6);
    } else {
        decode_tile_v4cs<52, 12, 11>(in52, anchors, 0.9f, 8.0f,
                                     bid - (NBLK13 + NBLK26),
                                     out + (size_t)CUM26 * 6);
    }
}

extern "C" void kernel_launch(void* const* d_in, const int* in_sizes, int n_in,
                              void* d_out, int out_size, void* d_ws, size_t ws_size,
                              hipStream_t stream) {
    const float* in13    = (const float*)d_in[0];
    const float* in26    = (const float*)d_in[1];
    const float* in52    = (const float*)d_in[2];
    const float* anchors = (const float*)d_in[3];
    float* out = (float*)d_out;

    const int blocks = NBLK13 + NBLK26 + NBLK52;   // 1440
    detector_decode<<<blocks, 256, 0, stream>>>(in13, in26, in52, anchors, out);
}